// Round 1
// baseline (694.609 us; speedup 1.0000x reference)
//
#include <hip/hip_runtime.h>
#include <hip/hip_bf16.h>
#include <math.h>

#define NROW 8192
#define DDIM 256
#define KNEG 4088        // (8192-16)/2
#define NBIN 256

typedef __attribute__((ext_vector_type(8))) short short8;
typedef __attribute__((ext_vector_type(4))) float f32x4;
typedef __attribute__((ext_vector_type(4))) unsigned short u16x4;
typedef unsigned short u16;

// ---------------- workspace layout (bytes) ----------------
#define H_OFF      0u
#define H_BYTES    (NROW * NBIN * 4u)          // 8 MiB histogram
#define XB_OFF     (H_OFF + H_BYTES)           // bf16 copy of X, 4 MiB
#define XB_BYTES   (NROW * DDIM * 2u)
#define SMALL_OFF  (XB_OFF + XB_BYTES)         // 12 MiB
#define S_OFF      (SMALL_OFF)                 // colsum s[256]
#define SG_OFF     (S_OFF + 1024u)             // S scalar
#define TOT_OFF    (SG_OFF + 4u)               // total accumulator
#define ZERO2_BYTES (1024u + 8u)
#define SQ_OFF     (SMALL_OFF + 4096u)         // sq[8192]
#define SCALE_OFF  (SQ_OFF + NROW * 4u)
#define DAP_OFF    (SCALE_OFF + NROW * 4u)
#define CB_OFF     (DAP_OFF + NROW * 4u)       // int
#define RANK_OFF   (CB_OFF + NROW * 4u)        // int

__device__ __forceinline__ u16 f2bf(float f) {
    unsigned u = __float_as_uint(f);
    unsigned r = (u + 0x7FFFu + ((u >> 16) & 1u)) >> 16;   // RNE
    return (u16)r;
}

// K1a: sq[row] = ||x_row||^2 ; Xb = bf16(X).  One wave per row.
__global__ void kprep(const float* __restrict__ X, u16* __restrict__ Xb,
                      float* __restrict__ sq) {
    int w = threadIdx.x >> 6, lane = threadIdx.x & 63;
    int row = blockIdx.x * 4 + w;
    float4 x = reinterpret_cast<const float4*>(X + row * DDIM)[lane];
    u16x4 bv;
    bv.x = f2bf(x.x); bv.y = f2bf(x.y); bv.z = f2bf(x.z); bv.w = f2bf(x.w);
    reinterpret_cast<u16x4*>(Xb + row * DDIM)[lane] = bv;
    float ss = x.x * x.x + x.y * x.y + x.z * x.z + x.w * x.w;
    for (int o = 32; o; o >>= 1) ss += __shfl_down(ss, o, 64);
    if (lane == 0) sq[row] = ss;
}

// K1c: colsum s[d] and S = sum(sq). 32 blocks x 256 threads.
__global__ void kcolsum(const float* __restrict__ X, const float* __restrict__ sq,
                        float* __restrict__ s, float* __restrict__ Sg) {
    __shared__ float red[256];
    int t = threadIdx.x;
    int r0 = blockIdx.x * 256;
    float p = 0.f;
    for (int r = 0; r < 256; ++r) p += X[(r0 + r) * DDIM + t];
    atomicAdd(&s[t], p);
    red[t] = sq[r0 + t];
    __syncthreads();
    for (int s2 = 128; s2 > 0; s2 >>= 1) {
        if (t < s2) red[t] += red[t + s2];
        __syncthreads();
    }
    if (t == 0) atomicAdd(Sg, red[0]);
}

// K1b: scale[i] = 1/rn_i via closed form. One wave per row.
__global__ void kscale(const float* __restrict__ X, const float* __restrict__ svec,
                       const float* __restrict__ Sg, const float* __restrict__ sq,
                       float* __restrict__ scale) {
    int w = threadIdx.x >> 6, lane = threadIdx.x & 63;
    int row = blockIdx.x * 4 + w;
    float4 x = reinterpret_cast<const float4*>(X + row * DDIM)[lane];
    float4 sv = reinterpret_cast<const float4*>(svec)[lane];
    float d = x.x * sv.x + x.y * sv.y + x.z * sv.z + x.w * sv.w;
    for (int o = 32; o; o >>= 1) d += __shfl_down(d, o, 64);
    if (lane == 0) {
        float rn2 = fmaf(8192.f, sq[row], Sg[0]) - 2.f * d;
        float rn = sqrtf(fmaxf(rn2, 0.f));
        scale[row] = (rn > 1e-5f) ? (1e-5f / rn) * 1e5f : 1e5f;
    }
}

// K2: positives. Block per 16-row identity group; exact fp32; 8th largest of 16.
__global__ __launch_bounds__(256) void kpos(const float* __restrict__ X,
                                            const float* __restrict__ sq,
                                            const float* __restrict__ scale,
                                            float* __restrict__ dap) {
    __shared__ float xs[16 * 257];
    __shared__ float pd[256];
    int tid = threadIdx.x;
    int i0 = blockIdx.x * 16;
    for (int idx = tid; idx < 4096; idx += 256) {
        int r = idx >> 8, c = idx & 255;
        xs[r * 257 + c] = X[(i0 + r) * DDIM + c];
    }
    __syncthreads();
    int a = tid >> 4, b = tid & 15;
    const float* pa = &xs[a * 257];
    const float* pb = &xs[b * 257];
    float dot = 0.f;
#pragma unroll 4
    for (int k = 0; k < 256; ++k) dot = fmaf(pa[k], pb[k], dot);
    float d2 = sq[i0 + a] + sq[i0 + b] - 2.f * dot;
    pd[a * 16 + b] = sqrtf(fmaxf(d2, 1e-12f));
    __syncthreads();
    if (tid < 16) {
        float top[8];
#pragma unroll
        for (int j = 0; j < 8; ++j) top[j] = -1e30f;
        for (int j = 0; j < 16; ++j) {
            float vv = pd[tid * 16 + j];
            if (vv > top[7]) {
                int p = 7;
                while (p > 0 && top[p - 1] < vv) { top[p] = top[p - 1]; --p; }
                top[p] = vv;
            }
        }
        dap[i0 + tid] = scale[i0 + tid] * top[7];
    }
}

// K3/K4: fused bf16-MFMA GEMM + per-row histogram of v = sq_j - 2*G_ij over
// negatives. Block = 64 rows (4 waves x 16) x 128 col-tiles (1/4 of columns).
// FINE=0: coarse bins [0,512)/256.  FINE=1: 256 fine bins inside selected bin.
template <int FINE>
__global__ __launch_bounds__(256, 2) void khist(const u16* __restrict__ Xb,
                                                const float* __restrict__ sq,
                                                unsigned* __restrict__ H,
                                                const int* __restrict__ cbsel) {
    __shared__ unsigned hist[64 * NBIN];
    const int tid = threadIdx.x;
    for (int i = tid; i < 64 * NBIN; i += 256) hist[i] = 0;
    const int rb = blockIdx.x >> 2;
    const int cs = blockIdx.x & 3;
    const int w = tid >> 6;
    const int lane = tid & 63;
    const int quad = lane >> 4;
    const int lc = lane & 15;
    const int i0 = rb * 64 + w * 16;
    const int idw = rb * 4 + w;   // col-tile holding this wave's positives

    short8 a[8];
    const int arow = i0 + lc;
#pragma unroll
    for (int kf = 0; kf < 8; ++kf)
        a[kf] = *reinterpret_cast<const short8*>(Xb + (arow * DDIM + kf * 32 + quad * 8));

    int mycb[4];
    float mylo[4];
    if (FINE) {
#pragma unroll
        for (int r = 0; r < 4; ++r) {
            int row = i0 + quad * 4 + r;
            mycb[r] = cbsel[row];
            mylo[r] = 2.f * (float)mycb[r];
        }
    }
    __syncthreads();

    for (int t = 0; t < 128; ++t) {
        const int ct = cs * 128 + t;
        if (ct == idw) continue;                 // skip positives (wave-uniform)
        const int bcol = ct * 16 + lc;
        const float sqj = sq[bcol];
        short8 b[8];
#pragma unroll
        for (int kf = 0; kf < 8; ++kf)
            b[kf] = *reinterpret_cast<const short8*>(Xb + (bcol * DDIM + kf * 32 + quad * 8));
        f32x4 c0 = {0.f, 0.f, 0.f, 0.f}, c1 = {0.f, 0.f, 0.f, 0.f};
#pragma unroll
        for (int kf = 0; kf < 8; kf += 2) {
            c0 = __builtin_amdgcn_mfma_f32_16x16x32_bf16(a[kf], b[kf], c0, 0, 0, 0);
            c1 = __builtin_amdgcn_mfma_f32_16x16x32_bf16(a[kf + 1], b[kf + 1], c1, 0, 0, 0);
        }
#pragma unroll
        for (int r = 0; r < 4; ++r) {
            float g = c0[r] + c1[r];
            float v = fmaf(-2.f, g, sqj);
            int rl = w * 16 + quad * 4 + r;
            int bbin = (int)(v * 0.5f);
            bbin = bbin < 0 ? 0 : (bbin > 255 ? 255 : bbin);
            if (!FINE) {
                atomicAdd(&hist[rl * NBIN + bbin], 1u);
            } else if (bbin == mycb[r]) {
                int fb = (int)((v - mylo[r]) * 128.f);
                fb = fb < 0 ? 0 : (fb > 255 ? 255 : fb);
                atomicAdd(&hist[rl * NBIN + fb], 1u);
            }
        }
    }
    __syncthreads();
    for (int i = tid; i < 64 * NBIN; i += 256) {
        unsigned cval = hist[i];
        if (cval) atomicAdd(&H[(rb * 64 + (i >> 8)) * NBIN + (i & 255)], cval);
    }
}

// K3b: per-row scan of coarse histogram from the top; emit bin + residual rank.
__global__ void kscan1(const unsigned* __restrict__ H, int* __restrict__ cbsel,
                       int* __restrict__ rankArr) {
    int i = blockIdx.x * 256 + threadIdx.x;
    unsigned cum = 0;
    int cb = 0, rk = 1;
    for (int b = NBIN - 1; b >= 0; --b) {
        unsigned h = H[i * NBIN + b];
        cum += h;
        if (cum >= (unsigned)KNEG) {
            cb = b;
            rk = KNEG - (int)(cum - h);
            break;
        }
    }
    cbsel[i] = cb;
    rankArr[i] = rk;
}

// K4b: per-row scan of fine histogram; reconstruct dist_an, accumulate |an-ap|.
__global__ void kscan2(const unsigned* __restrict__ H, const int* __restrict__ cbsel,
                       const int* __restrict__ rankArr, const float* __restrict__ sq,
                       const float* __restrict__ scale, const float* __restrict__ dap,
                       float* __restrict__ total) {
    __shared__ float red[256];
    int i = blockIdx.x * 256 + threadIdx.x;
    unsigned cum = 0;
    int target = rankArr[i];
    float v = 2.f * (float)cbsel[i] + 1.f;   // fallback: bin middle
    for (int b = NBIN - 1; b >= 0; --b) {
        unsigned h = H[i * NBIN + b];
        cum += h;
        if (cum >= (unsigned)target) {
            v = 2.f * (float)cbsel[i] + ((float)b + 0.5f) * (2.f / 256.f);
            break;
        }
    }
    float d2 = sq[i] + v;
    float dan = scale[i] * sqrtf(fmaxf(d2, 1e-12f));
    float diff = fabsf(dan - dap[i]);
    red[threadIdx.x] = diff;
    __syncthreads();
    for (int s2 = 128; s2 > 0; s2 >>= 1) {
        if (threadIdx.x < s2) red[threadIdx.x] += red[threadIdx.x + s2];
        __syncthreads();
    }
    if (threadIdx.x == 0) atomicAdd(total, red[0]);
}

__global__ void kfinal(const float* __restrict__ total, float* __restrict__ out) {
    out[0] = log10f(8192.f / total[0]);
}

extern "C" void kernel_launch(void* const* d_in, const int* in_sizes, int n_in,
                              void* d_out, int out_size, void* d_ws, size_t ws_size,
                              hipStream_t stream) {
    const float* X = (const float*)d_in[0];
    char* ws = (char*)d_ws;
    unsigned* H = (unsigned*)(ws + H_OFF);
    u16* Xb = (u16*)(ws + XB_OFF);
    float* svec = (float*)(ws + S_OFF);
    float* Sg = (float*)(ws + SG_OFF);
    float* total = (float*)(ws + TOT_OFF);
    float* sq = (float*)(ws + SQ_OFF);
    float* scale = (float*)(ws + SCALE_OFF);
    float* dap = (float*)(ws + DAP_OFF);
    int* cb = (int*)(ws + CB_OFF);
    int* rank = (int*)(ws + RANK_OFF);
    float* out = (float*)d_out;

    hipMemsetAsync(H, 0, H_BYTES, stream);
    hipMemsetAsync(ws + S_OFF, 0, ZERO2_BYTES, stream);
    kprep<<<NROW / 4, 256, 0, stream>>>(X, Xb, sq);
    kcolsum<<<NROW / 256, 256, 0, stream>>>(X, sq, svec, Sg);
    kscale<<<NROW / 4, 256, 0, stream>>>(X, svec, Sg, sq, scale);
    kpos<<<NROW / 16, 256, 0, stream>>>(X, sq, scale, dap);
    khist<0><<<512, 256, 0, stream>>>(Xb, sq, H, nullptr);
    kscan1<<<NROW / 256, 256, 0, stream>>>(H, cb, rank);
    hipMemsetAsync(H, 0, H_BYTES, stream);
    khist<1><<<512, 256, 0, stream>>>(Xb, sq, H, cb);
    kscan2<<<NROW / 256, 256, 0, stream>>>(H, cb, rank, sq, scale, dap, total);
    kfinal<<<1, 1, 0, stream>>>(total, out);
}

// Round 2
// 239.512 us; speedup vs baseline: 2.9001x; 2.9001x over previous
//
#include <hip/hip_runtime.h>
#include <hip/hip_bf16.h>
#include <math.h>

#define NROW 8192
#define DDIM 256
#define KNEG 4088        // (8192-16)/2
#define NBIN 64          // coarse bins, width 8 over v in [0,512)

typedef __attribute__((ext_vector_type(8))) short short8;
typedef __attribute__((ext_vector_type(4))) float f32x4;
typedef __attribute__((ext_vector_type(4))) unsigned short u16x4;
typedef unsigned short u16;

// ---------------- workspace layout (bytes) ----------------
#define H_OFF      0u
#define H_BYTES    (NROW * NBIN * 4u)          // 2 MiB histogram [row][bin]
#define XB_OFF     (H_OFF + H_BYTES)           // bf16 copy of X, 4 MiB
#define XB_BYTES   (NROW * DDIM * 2u)
#define SVEC_OFF   (XB_OFF + XB_BYTES)         // colsum s[256] floats
#define SG_OFF     (SVEC_OFF + 1024u)          // S scalar
#define ZERO2_BYTES 1040u                      // svec + Sg region
#define SQ_OFF     (SVEC_OFF + 2048u)          // sq[8192]
#define DAP_OFF    (SQ_OFF + NROW * 4u)        // raw (unscaled) dist_ap
#define PART_OFF   (DAP_OFF + NROW * 4u)       // per-block partials [2048]

__device__ __forceinline__ u16 f2bf(float f) {
    unsigned u = __float_as_uint(f);
    unsigned r = (u + 0x7FFFu + ((u >> 16) & 1u)) >> 16;   // RNE
    return (u16)r;
}

// K1: sq[row] = ||x_row||^2 ; Xb = bf16(X).  One wave per row.
__global__ void kprep(const float* __restrict__ X, u16* __restrict__ Xb,
                      float* __restrict__ sq) {
    int w = threadIdx.x >> 6, lane = threadIdx.x & 63;
    int row = blockIdx.x * 4 + w;
    float4 x = reinterpret_cast<const float4*>(X + row * DDIM)[lane];
    u16x4 bv;
    bv.x = f2bf(x.x); bv.y = f2bf(x.y); bv.z = f2bf(x.z); bv.w = f2bf(x.w);
    reinterpret_cast<u16x4*>(Xb + row * DDIM)[lane] = bv;
    float ss = x.x * x.x + x.y * x.y + x.z * x.z + x.w * x.w;
    for (int o = 32; o; o >>= 1) ss += __shfl_down(ss, o, 64);
    if (lane == 0) sq[row] = ss;
}

// K2: colsum svec[d] over all rows, plus Sg = sum(sq). 256 blocks x 256 thr.
__global__ void kcolsum(const float* __restrict__ X, const float* __restrict__ sq,
                        float* __restrict__ svec, float* __restrict__ Sg) {
    __shared__ float red[32];
    int t = threadIdx.x;
    int r0 = blockIdx.x * 32;
    float p = 0.f;
    for (int r = 0; r < 32; ++r) p += X[(r0 + r) * DDIM + t];
    atomicAdd(&svec[t], p);
    if (t < 32) red[t] = sq[r0 + t];
    __syncthreads();
    if (t == 0) {
        float s = 0.f;
        for (int r = 0; r < 32; ++r) s += red[r];
        atomicAdd(Sg, s);
    }
}

// K3: positives, exact fp32. Block per 16-row identity group. Stores RAW 8th-largest.
__global__ __launch_bounds__(256) void kpos(const float* __restrict__ X,
                                            const float* __restrict__ sq,
                                            float* __restrict__ dap) {
    __shared__ float xs[16 * 257];
    __shared__ float pd[256];
    int tid = threadIdx.x;
    int i0 = blockIdx.x * 16;
    for (int idx = tid; idx < 4096; idx += 256) {
        int r = idx >> 8, c = idx & 255;
        xs[r * 257 + c] = X[(i0 + r) * DDIM + c];
    }
    __syncthreads();
    int a = tid >> 4, b = tid & 15;
    const float* pa = &xs[a * 257];
    const float* pb = &xs[b * 257];
    float dot = 0.f;
#pragma unroll 4
    for (int k = 0; k < 256; ++k) dot = fmaf(pa[k], pb[k], dot);
    float d2 = sq[i0 + a] + sq[i0 + b] - 2.f * dot;
    pd[a * 16 + b] = sqrtf(fmaxf(d2, 1e-12f));
    __syncthreads();
    if (tid < 16) {
        float top[8];
#pragma unroll
        for (int j = 0; j < 8; ++j) top[j] = -1e30f;
        for (int j = 0; j < 16; ++j) {
            float vv = pd[tid * 16 + j];
            if (vv > top[7]) {
                int p = 7;
                while (p > 0 && top[p - 1] < vv) { top[p] = top[p - 1]; --p; }
                top[p] = vv;
            }
        }
        dap[i0 + tid] = top[7];
    }
}

// K4: single-pass fused bf16-MFMA GEMM + per-row 64-bin histogram of
// v = sq_j - 2*G_ij over negatives.
// Grid: 256 blocks = 32 row-groups x 8 col-groups. Block: 256 rows x 1024 cols.
// Wave w holds rows rb+w*64..+64 (4 subtiles of 16) as B-operand fragments in
// REGISTERS (128 VGPRs); col tiles stream through LDS (coalesced staging,
// pad 264 -> conflict-optimal b128 reads), double-buffered.
// Operand swap: A=cols, B=rows => output N(lc)=row, M(quad*4+r)=col, so each
// lane's outputs live in 4 fixed hist rows. Hist is bin-major, stride 132,
// u16-packed row pairs (counts <= 1024): 33 KB. Total LDS 50.7 KB.
__global__ __launch_bounds__(256, 1) void khist(const u16* __restrict__ Xb,
                                                const float* __restrict__ sq,
                                                unsigned* __restrict__ H) {
    __shared__ unsigned hist[NBIN * 132];
    __shared__ u16 ast[2][16 * 264];
    const int tid = threadIdx.x;
    const int rg = blockIdx.x & 31, cg = blockIdx.x >> 5;
    const int rb = rg * 256;
    const int t0 = cg * 64;                    // first global col-tile index
    const int w = tid >> 6, lane = tid & 63, quad = lane >> 4, lc = lane & 15;

    for (int i = tid; i < NBIN * 132; i += 256) hist[i] = 0;

    // row fragments (B operand): B[k=quad*8+j][n=lc] = Xb[row][k]
    short8 b[4][8];
#pragma unroll
    for (int st = 0; st < 4; ++st) {
        const u16* rp = Xb + (rb + w * 64 + st * 16 + lc) * DDIM + quad * 8;
#pragma unroll
        for (int kf = 0; kf < 8; ++kf)
            b[st][kf] = *reinterpret_cast<const short8*>(rp + kf * 32);
    }
    int pt[4];
#pragma unroll
    for (int st = 0; st < 4; ++st) pt[st] = (rb + w * 64 + st * 16) >> 4;

    // stage tile 0 into buffer 0 (chunk c: row=c>>5, 8-elem offset (c&31)*8)
    {
        int c0 = tid, c1 = tid + 256;
        short8 g0 = *reinterpret_cast<const short8*>(Xb + (t0 * 16 + (c0 >> 5)) * DDIM + (c0 & 31) * 8);
        short8 g1 = *reinterpret_cast<const short8*>(Xb + (t0 * 16 + (c1 >> 5)) * DDIM + (c1 & 31) * 8);
        *reinterpret_cast<short8*>(&ast[0][(c0 >> 5) * 264 + (c0 & 31) * 8]) = g0;
        *reinterpret_cast<short8*>(&ast[0][(c1 >> 5) * 264 + (c1 & 31) * 8]) = g1;
    }
    __syncthreads();

    for (int t = 0; t < 64; ++t) {
        const int gct = t0 + t;
        const int cur = t & 1;
        short8 s0, s1;
        if (t + 1 < 64) {           // issue next-tile global loads early
            int c0 = tid, c1 = tid + 256;
            const u16* nb = Xb + (gct + 1) * 16 * DDIM;
            s0 = *reinterpret_cast<const short8*>(nb + (c0 >> 5) * DDIM + (c0 & 31) * 8);
            s1 = *reinterpret_cast<const short8*>(nb + (c1 >> 5) * DDIM + (c1 & 31) * 8);
        }
        // A fragments (cols) from LDS: A[m=lc][k=quad*8+j]
        short8 a[8];
#pragma unroll
        for (int kf = 0; kf < 8; ++kf)
            a[kf] = *reinterpret_cast<const short8*>(&ast[cur][lc * 264 + kf * 32 + quad * 8]);
        f32x4 c[4];
#pragma unroll
        for (int st = 0; st < 4; ++st) c[st] = (f32x4){0.f, 0.f, 0.f, 0.f};
#pragma unroll
        for (int kf = 0; kf < 8; ++kf)
#pragma unroll
            for (int st = 0; st < 4; ++st)
                c[st] = __builtin_amdgcn_mfma_f32_16x16x32_bf16(a[kf], b[st][kf], c[st], 0, 0, 0);
        float sq4[4];
#pragma unroll
        for (int r = 0; r < 4; ++r) sq4[r] = sq[gct * 16 + quad * 4 + r];
#pragma unroll
        for (int st = 0; st < 4; ++st) {
            if (gct != pt[st]) {               // skip the positive tile (wave-uniform)
                const int rl = w * 64 + st * 16 + lc;
                const unsigned val = (rl < 128) ? 1u : 65536u;
                const int rp = rl & 127;
#pragma unroll
                for (int r = 0; r < 4; ++r) {
                    float v = fmaf(-2.f, c[st][r], sq4[r]);
                    int bin = (int)(v * 0.125f);
                    bin = bin < 0 ? 0 : (bin > 63 ? 63 : bin);
                    atomicAdd(&hist[bin * 132 + rp], val);
                }
            }
        }
        if (t + 1 < 64) {
            int c0 = tid, c1 = tid + 256;
            *reinterpret_cast<short8*>(&ast[1 - cur][(c0 >> 5) * 264 + (c0 & 31) * 8]) = s0;
            *reinterpret_cast<short8*>(&ast[1 - cur][(c1 >> 5) * 264 + (c1 & 31) * 8]) = s1;
        }
        __syncthreads();
    }

    // flush packed LDS hist -> global H[row][bin]
    for (int i = tid; i < NBIN * 128; i += 256) {
        int bin = i >> 7, rp = i & 127;
        unsigned wv = hist[bin * 132 + rp];
        unsigned lo = wv & 0xFFFFu, hi = wv >> 16;
        if (lo) atomicAdd(&H[(rb + rp) * NBIN + bin], lo);
        if (hi) atomicAdd(&H[(rb + 128 + rp) * NBIN + bin], hi);
    }
}

// K5: wave per row. Closed-form scale, suffix-scan of 64-bin hist via shuffles,
// rank interpolation within the selected bin, |dan-dap|*scale, block partial.
__global__ __launch_bounds__(256) void kscan(const float* __restrict__ X,
                                             const unsigned* __restrict__ H,
                                             const float* __restrict__ svec,
                                             const float* __restrict__ Sg,
                                             const float* __restrict__ sq,
                                             const float* __restrict__ dap,
                                             float* __restrict__ partial) {
    __shared__ float wsum[4];
    int w = threadIdx.x >> 6, lane = threadIdx.x & 63;
    int row = blockIdx.x * 4 + w;
    float4 xv = reinterpret_cast<const float4*>(X)[row * 64 + lane];
    float4 sv = reinterpret_cast<const float4*>(svec)[lane];
    float d = xv.x * sv.x + xv.y * sv.y + xv.z * sv.z + xv.w * sv.w;
#pragma unroll
    for (int o = 32; o; o >>= 1) d += __shfl_xor(d, o, 64);

    unsigned h = H[row * NBIN + lane];
    unsigned cum = h;
#pragma unroll
    for (int o = 1; o < 64; o <<= 1) {
        unsigned vv = (unsigned)__shfl_down((int)cum, o, 64);
        if (lane + o < 64) cum += vv;
    }
    unsigned long long mask = __ballot(cum >= (unsigned)KNEG);
    int bstar = 63 - __builtin_clzll(mask);
    unsigned hs = (unsigned)__shfl((int)h, bstar, 64);
    unsigned cums = (unsigned)__shfl((int)cum, bstar, 64);
    int rk = KNEG - (int)(cums - hs);          // in [1, hs]
    float vest = 8.f * (float)(bstar + 1) - 8.f * ((float)rk - 0.5f) / (float)hs;

    float sqi = sq[row];
    float rn2 = fmaf(8192.f, sqi, Sg[0]) - 2.f * d;
    float scale = 1.f / sqrtf(fmaxf(rn2, 1e-30f));   // (1e-5/rn)*1e5
    float dan = sqrtf(fmaxf(sqi + vest, 1e-12f));
    float diff = fabsf(dan - dap[row]) * scale;
    if (lane == 0) wsum[w] = diff;
    __syncthreads();
    if (threadIdx.x == 0)
        partial[blockIdx.x] = wsum[0] + wsum[1] + wsum[2] + wsum[3];
}

__global__ void kfinal(const float* __restrict__ partial, float* __restrict__ out) {
    __shared__ float red[256];
    float s = 0.f;
    for (int i = threadIdx.x; i < 2048; i += 256) s += partial[i];
    red[threadIdx.x] = s;
    __syncthreads();
    for (int o = 128; o; o >>= 1) {
        if (threadIdx.x < o) red[threadIdx.x] += red[threadIdx.x + o];
        __syncthreads();
    }
    if (threadIdx.x == 0) out[0] = log10f(8192.f / red[0]);
}

extern "C" void kernel_launch(void* const* d_in, const int* in_sizes, int n_in,
                              void* d_out, int out_size, void* d_ws, size_t ws_size,
                              hipStream_t stream) {
    const float* X = (const float*)d_in[0];
    char* ws = (char*)d_ws;
    unsigned* H = (unsigned*)(ws + H_OFF);
    u16* Xb = (u16*)(ws + XB_OFF);
    float* svec = (float*)(ws + SVEC_OFF);
    float* Sg = (float*)(ws + SG_OFF);
    float* sq = (float*)(ws + SQ_OFF);
    float* dap = (float*)(ws + DAP_OFF);
    float* partial = (float*)(ws + PART_OFF);
    float* out = (float*)d_out;

    hipMemsetAsync(H, 0, H_BYTES, stream);
    hipMemsetAsync(ws + SVEC_OFF, 0, ZERO2_BYTES, stream);
    kprep<<<NROW / 4, 256, 0, stream>>>(X, Xb, sq);
    kcolsum<<<NROW / 32, 256, 0, stream>>>(X, sq, svec, Sg);
    kpos<<<NROW / 16, 256, 0, stream>>>(X, sq, dap);
    khist<<<256, 256, 0, stream>>>(Xb, sq, H);
    kscan<<<NROW / 4, 256, 0, stream>>>(X, H, svec, Sg, sq, dap, partial);
    kfinal<<<1, 256, 0, stream>>>(partial, out);
}

// Round 3
// 171.629 us; speedup vs baseline: 4.0472x; 1.3955x over previous
//
#include <hip/hip_runtime.h>
#include <math.h>

#define NROW 8192
#define DDIM 256

typedef __attribute__((ext_vector_type(8))) short short8;
typedef __attribute__((ext_vector_type(4))) float f32x4;
typedef __attribute__((ext_vector_type(4))) unsigned short u16x4;
typedef unsigned short u16;

// ---------------- workspace layout (bytes) ----------------
// XbT: bf16 X in MFMA-fragment layout: element ((tile*8+kf)*64 + lane)*8..+8
//      = X[tile*16 + (lane&15)][kf*32 + (lane>>4)*8 ..+8]
#define XBT_OFF    0u
#define XBT_BYTES  (NROW * DDIM * 2u)          // 4 MiB
#define SQ_OFF     (XBT_OFF + XBT_BYTES)
#define SVEC_OFF   (SQ_OFF + NROW * 4u)        // colsum s[256]
#define SG_OFF     (SVEC_OFF + 1024u)          // S scalar
#define ZERO2_BYTES 1028u
#define DAP_OFF    (SVEC_OFF + 2048u)
#define T_OFF      (DAP_OFF + NROW * 4u)
#define S1_OFF     (T_OFF + NROW * 4u)
#define S2_OFF     (S1_OFF + NROW * 4u)        // S1,S2 contiguous (one memset)
#define PART_OFF   (S2_OFF + NROW * 4u)

__device__ __forceinline__ u16 f2bf(float f) {
    unsigned u = __float_as_uint(f);
    unsigned r = (u + 0x7FFFu + ((u >> 16) & 1u)) >> 16;   // RNE
    return (u16)r;
}

// K1: block per 16-row tile. Coalesced fp32 read -> bf16 -> LDS transpose ->
// coalesced XbT write in MFMA fragment layout. Also sq[row] via wave reduce.
__global__ __launch_bounds__(256) void kprep(const float* __restrict__ X,
                                             u16* __restrict__ XbT,
                                             float* __restrict__ sq) {
    __shared__ u16 xs[16 * 264];
    int t = threadIdx.x, w = t >> 6, lane = t & 63;
    int tile = blockIdx.x;
#pragma unroll
    for (int it = 0; it < 4; ++it) {
        int r = w + 4 * it;                       // one full row per wave
        float4 x = reinterpret_cast<const float4*>(X + (tile * 16 + r) * DDIM)[lane];
        u16x4 bv;
        bv.x = f2bf(x.x); bv.y = f2bf(x.y); bv.z = f2bf(x.z); bv.w = f2bf(x.w);
        *reinterpret_cast<u16x4*>(&xs[r * 264 + lane * 4]) = bv;
        float ss = x.x * x.x + x.y * x.y + x.z * x.z + x.w * x.w;
#pragma unroll
        for (int o = 32; o; o >>= 1) ss += __shfl_down(ss, o, 64);
        if (lane == 0) sq[tile * 16 + r] = ss;
    }
    __syncthreads();
#pragma unroll
    for (int g = t; g < 512; g += 256) {
        int kf = g >> 6, l2 = g & 63, quad = l2 >> 4, lc = l2 & 15;
        short8 v = *reinterpret_cast<const short8*>(&xs[lc * 264 + kf * 32 + quad * 8]);
        *reinterpret_cast<short8*>(XbT + tile * 4096 + g * 8) = v;
    }
}

// K2: colsum svec[d] over all rows, plus Sg = sum(sq).
__global__ void kcolsum(const float* __restrict__ X, const float* __restrict__ sq,
                        float* __restrict__ svec, float* __restrict__ Sg) {
    __shared__ float red[32];
    int t = threadIdx.x;
    int r0 = blockIdx.x * 32;
    float p = 0.f;
    for (int r = 0; r < 32; ++r) p += X[(r0 + r) * DDIM + t];
    atomicAdd(&svec[t], p);
    if (t < 32) red[t] = sq[r0 + t];
    __syncthreads();
    if (t == 0) {
        float s = 0.f;
        for (int r = 0; r < 32; ++r) s += red[r];
        atomicAdd(Sg, s);
    }
}

// K3: positives, exact fp32. Block per 16-row identity group. RAW 8th-largest.
__global__ __launch_bounds__(256) void kpos(const float* __restrict__ X,
                                            const float* __restrict__ sq,
                                            float* __restrict__ dap) {
    __shared__ float xs[16 * 257];
    __shared__ float pd[256];
    int tid = threadIdx.x;
    int i0 = blockIdx.x * 16;
    for (int idx = tid; idx < 4096; idx += 256) {
        int r = idx >> 8, c = idx & 255;
        xs[r * 257 + c] = X[(i0 + r) * DDIM + c];
    }
    __syncthreads();
    int a = tid >> 4, b = tid & 15;
    const float* pa = &xs[a * 257];
    const float* pb = &xs[b * 257];
    float dot = 0.f;
#pragma unroll 4
    for (int k = 0; k < 256; ++k) dot = fmaf(pa[k], pb[k], dot);
    float d2 = sq[i0 + a] + sq[i0 + b] - 2.f * dot;
    pd[a * 16 + b] = sqrtf(fmaxf(d2, 1e-12f));
    __syncthreads();
    if (tid < 16) {
        float top[8];
#pragma unroll
        for (int j = 0; j < 8; ++j) top[j] = -1e30f;
        for (int j = 0; j < 16; ++j) {
            float vv = pd[tid * 16 + j];
            if (vv > top[7]) {
                int p = 7;
                while (p > 0 && top[p - 1] < vv) { top[p] = top[p - 1]; --p; }
                top[p] = vv;
            }
        }
        dap[i0 + tid] = top[7];
    }
}

// K4: sample pass. 128 blocks x 64 rows; 16 sample col-tiles (every 32nd).
// Per-quad LDS hists (region stride 2049 words -> quad-offset banks, rows give
// distinct banks within a quad) -> near-zero conflicts. T[row] = interpolated
// rank-128-of-256 estimate of the negatives' median of v = sq_j - 2*x_i.x_j.
#define SH_STRIDE 2049
__global__ __launch_bounds__(256) void ksample(const u16* __restrict__ XbT,
                                               const float* __restrict__ sq,
                                               float* __restrict__ T) {
    __shared__ unsigned hist[4 * SH_STRIDE];      // 32.8 KB
    int t = threadIdx.x, w = t >> 6, lane = t & 63, quad = lane >> 4, lc = lane & 15;
    for (int i = t; i < 4 * SH_STRIDE; i += 256) hist[i] = 0;
    int rb = blockIdx.x * 64;
    int rt = (rb >> 4) + w;
    short8 b[8];
#pragma unroll
    for (int kf = 0; kf < 8; ++kf)
        b[kf] = *reinterpret_cast<const short8*>(XbT + ((rt * 8 + kf) * 64 + lane) * 8);
    int rl = w * 16 + lc;
    unsigned val = (rl < 32) ? 1u : 65536u;
    unsigned* hq = hist + quad * SH_STRIDE + (rl & 31);
    __syncthreads();
    for (int it = 0; it < 16; ++it) {
        int ct = it * 32;
        short8 a[8];
#pragma unroll
        for (int kf = 0; kf < 8; ++kf)
            a[kf] = *reinterpret_cast<const short8*>(XbT + ((ct * 8 + kf) * 64 + lane) * 8);
        f32x4 c = {0.f, 0.f, 0.f, 0.f};
#pragma unroll
        for (int kf = 0; kf < 8; ++kf)
            c = __builtin_amdgcn_mfma_f32_16x16x32_bf16(a[kf], b[kf], c, 0, 0, 0);
        float4 sq4 = reinterpret_cast<const float4*>(sq + ct * 16)[quad];
        const float* sp = (const float*)&sq4;
#pragma unroll
        for (int r = 0; r < 4; ++r) {
            float v = fmaf(-2.f, c[r], sp[r]);
            int bin = (int)(v * 0.125f);
            bin = bin < 0 ? 0 : (bin > 63 ? 63 : bin);
            atomicAdd(hq + bin * 32, val);
        }
    }
    __syncthreads();
    if (t < 64) {
        unsigned shift = (t < 32) ? 0 : 16;
        int rp = t & 31;
        unsigned cum = 0;
        float Tv = 256.f;
        for (int bb = 63; bb >= 0; --bb) {
            unsigned h = 0;
#pragma unroll
            for (int q = 0; q < 4; ++q)
                h += (hist[q * SH_STRIDE + bb * 32 + rp] >> shift) & 0xFFFFu;
            cum += h;
            if (cum >= 128u) {
                int rk = 128 - (int)(cum - h);
                Tv = 8.f * (float)(bb + 1) - 8.f * ((float)rk - 0.5f) / (float)h;
                break;
            }
        }
        T[rb + t] = Tv;
    }
}

// K5: main pass. 1024 blocks = 32 rg x 32 cg; block = 256 rows x 256 cols.
// All fragments stream from XbT (global, L1/L2) - no LDS, no barriers.
// Per value: two clamped ramps (smoothed CDF at T-6 / T+6, half-width 9)
// accumulated in registers; quad-reduce via shfl; one float atomic per row.
__global__ __launch_bounds__(256, 2) void kcount(const u16* __restrict__ XbT,
                                                 const float* __restrict__ sq,
                                                 const float* __restrict__ T,
                                                 float* __restrict__ S1,
                                                 float* __restrict__ S2) {
    int t = threadIdx.x, w = t >> 6, lane = t & 63, quad = lane >> 4, lc = lane & 15;
    int rg = blockIdx.x & 31, cg = blockIdx.x >> 5;
    int rb = rg * 256;
    const float inv = 1.f / 18.f;
    short8 b[4][8];
    int rt[4];
    float l1s[4], l2s[4];
    float a1[4] = {0.f, 0.f, 0.f, 0.f}, a2[4] = {0.f, 0.f, 0.f, 0.f};
#pragma unroll
    for (int st = 0; st < 4; ++st) {
        rt[st] = (rb >> 4) + w * 4 + st;
#pragma unroll
        for (int kf = 0; kf < 8; ++kf)
            b[st][kf] = *reinterpret_cast<const short8*>(XbT + ((rt[st] * 8 + kf) * 64 + lane) * 8);
        float Tv = T[rb + w * 64 + st * 16 + lc];
        l1s[st] = (Tv - 15.f) * inv;              // ramp1 low edge * inv
        l2s[st] = (Tv - 3.f) * inv;               // ramp2 low edge * inv
    }
    for (int it = 0; it < 16; ++it) {
        int ct = cg * 16 + it;
        short8 a[8];
#pragma unroll
        for (int kf = 0; kf < 8; ++kf)
            a[kf] = *reinterpret_cast<const short8*>(XbT + ((ct * 8 + kf) * 64 + lane) * 8);
        f32x4 c[4];
#pragma unroll
        for (int st = 0; st < 4; ++st) c[st] = (f32x4){0.f, 0.f, 0.f, 0.f};
#pragma unroll
        for (int kf = 0; kf < 8; ++kf)
#pragma unroll
            for (int st = 0; st < 4; ++st)
                c[st] = __builtin_amdgcn_mfma_f32_16x16x32_bf16(a[kf], b[st][kf], c[st], 0, 0, 0);
        float4 sq4 = reinterpret_cast<const float4*>(sq + ct * 16)[quad];
        const float* sp = (const float*)&sq4;
#pragma unroll
        for (int st = 0; st < 4; ++st) {
            if (ct != rt[st]) {                   // skip positive tile (wave-uniform)
#pragma unroll
                for (int r = 0; r < 4; ++r) {
                    float v = fmaf(-2.f, c[st][r], sp[r]);
                    float r1 = fminf(fmaxf(fmaf(v, inv, -l1s[st]), 0.f), 1.f);
                    float r2 = fminf(fmaxf(fmaf(v, inv, -l2s[st]), 0.f), 1.f);
                    a1[st] += r1;
                    a2[st] += r2;
                }
            }
        }
    }
#pragma unroll
    for (int st = 0; st < 4; ++st) {
        float x1 = a1[st], x2 = a2[st];
        x1 += __shfl_xor(x1, 16, 64); x1 += __shfl_xor(x1, 32, 64);
        x2 += __shfl_xor(x2, 16, 64); x2 += __shfl_xor(x2, 32, 64);
        if (quad == 0) {
            int row = rb + w * 64 + st * 16 + lc;
            atomicAdd(&S1[row], x1);
            atomicAdd(&S2[row], x2);
        }
    }
}

// K6: wave per row. Closed-form renorm scale; linear inversion of smoothed
// counts -> dist_an; |dan-dap|*scale -> block partial.
__global__ __launch_bounds__(256) void kscan(const float* __restrict__ X,
                                             const float* __restrict__ svec,
                                             const float* __restrict__ Sg,
                                             const float* __restrict__ sq,
                                             const float* __restrict__ dap,
                                             const float* __restrict__ T,
                                             const float* __restrict__ S1,
                                             const float* __restrict__ S2,
                                             float* __restrict__ partial) {
    __shared__ float wsum[4];
    int w = threadIdx.x >> 6, lane = threadIdx.x & 63;
    int row = blockIdx.x * 4 + w;
    float4 xv = reinterpret_cast<const float4*>(X)[row * 64 + lane];
    float4 sv = reinterpret_cast<const float4*>(svec)[lane];
    float d = xv.x * sv.x + xv.y * sv.y + xv.z * sv.z + xv.w * sv.w;
#pragma unroll
    for (int o = 32; o; o >>= 1) d += __shfl_xor(d, o, 64);
    if (lane == 0) {
        float s1 = S1[row], s2 = S2[row];
        float f = fmaxf((s1 - s2) * (1.f / 12.f), 1.f);
        float Tv = T[row];
        float vest = (Tv - 6.f) + (s1 - 4087.5f) / f;
        vest = fminf(fmaxf(vest, Tv - 15.f), Tv + 15.f);
        float sqi = sq[row];
        float rn2 = fmaf(8192.f, sqi, Sg[0]) - 2.f * d;
        float scale = 1.f / sqrtf(fmaxf(rn2, 1e-30f));
        float dan = sqrtf(fmaxf(sqi + vest, 1e-12f));
        wsum[w] = fabsf(dan - dap[row]) * scale;
    }
    __syncthreads();
    if (threadIdx.x == 0)
        partial[blockIdx.x] = wsum[0] + wsum[1] + wsum[2] + wsum[3];
}

__global__ void kfinal(const float* __restrict__ partial, float* __restrict__ out) {
    __shared__ float red[256];
    float s = 0.f;
    for (int i = threadIdx.x; i < 2048; i += 256) s += partial[i];
    red[threadIdx.x] = s;
    __syncthreads();
    for (int o = 128; o; o >>= 1) {
        if (threadIdx.x < o) red[threadIdx.x] += red[threadIdx.x + o];
        __syncthreads();
    }
    if (threadIdx.x == 0) out[0] = log10f(8192.f / red[0]);
}

extern "C" void kernel_launch(void* const* d_in, const int* in_sizes, int n_in,
                              void* d_out, int out_size, void* d_ws, size_t ws_size,
                              hipStream_t stream) {
    const float* X = (const float*)d_in[0];
    char* ws = (char*)d_ws;
    u16* XbT = (u16*)(ws + XBT_OFF);
    float* sq = (float*)(ws + SQ_OFF);
    float* svec = (float*)(ws + SVEC_OFF);
    float* Sg = (float*)(ws + SG_OFF);
    float* dap = (float*)(ws + DAP_OFF);
    float* T = (float*)(ws + T_OFF);
    float* S1 = (float*)(ws + S1_OFF);
    float* S2 = (float*)(ws + S2_OFF);
    float* partial = (float*)(ws + PART_OFF);
    float* out = (float*)d_out;

    hipMemsetAsync(S1, 0, NROW * 8u, stream);            // S1+S2
    hipMemsetAsync(ws + SVEC_OFF, 0, ZERO2_BYTES, stream);
    kprep<<<NROW / 16, 256, 0, stream>>>(X, XbT, sq);
    kcolsum<<<NROW / 32, 256, 0, stream>>>(X, sq, svec, Sg);
    kpos<<<NROW / 16, 256, 0, stream>>>(X, sq, dap);
    ksample<<<NROW / 64, 256, 0, stream>>>(XbT, sq, T);
    kcount<<<1024, 256, 0, stream>>>(XbT, sq, T, S1, S2);
    kscan<<<NROW / 4, 256, 0, stream>>>(X, svec, Sg, sq, dap, T, S1, S2, partial);
    kfinal<<<1, 256, 0, stream>>>(partial, out);
}